// Round 5
// baseline (217.465 us; speedup 1.0000x reference)
//
#include <hip/hip_runtime.h>
#include <math.h>

#define TOKENS 16384
#define DIM    2048
#define NEXP   16
#define CHUNK  256                 // K-floats per chunk (1 KB per row)
#define NCHUNK (DIM / CHUNK)       // 8
#define TPB    16                  // tokens per block
#define NWAVE  4                   // waves per block (256 thr)

typedef float fvec4 __attribute__((ext_vector_type(4)));

// R13: barrier-free, LDS-free.  Post-mortems:
//   R8  (~30us): per-chunk __syncthreads = vmcnt(0) drain of x prefetch.
//   R12 (~45us): counted-barrier attempt; sched_barrier(0) pins defeat the
//                compiler scheduler (m141 signature) + lost nt on x evicted
//                W from L2 so the barrier waited on HBM.
//   R11 (~79us): barrier-free was right, but `W + lane4` made a PER-LANE
//                base pointer -> 16 divergent 64-bit address chains ->
//                acc spill (VGPR=84, WRITE_SIZE 8.4MB scratch).
// Fix here: W indexed as W[<compile-time const> + lane4] => uniform SGPR
// base + one shared voffset VGPR (saddr-form global_load_dwordx4), no
// per-lane pointer arithmetic.  readfirstlane(w) keeps x-row bases scalar.
// x: nontemporal (streams past L2, keeps 128KB W L2-resident), 1-chunk
// register prefetch; 512cy FMA/chunk x 3 waves/SIMD = ~1536cy wall per
// chunk >> 900cy HBM latency -> fully hidden, no sync of any kind.
// FMA chain order / butterfly / epilogue BIT-IDENTICAL to R8.
__global__ __launch_bounds__(256, 3) void gating_moe_kernel(
    const float* __restrict__ x,
    const float* __restrict__ noise,
    const float* __restrict__ W,
    const float* __restrict__ b,
    float* __restrict__ out)
{
    const int tid  = threadIdx.x;
    const int lane = tid & 63;
    const int w    = __builtin_amdgcn_readfirstlane(tid >> 6);   // wave 0..3
    const int block_base = blockIdx.x * TPB;
    const int lane4 = lane * 4;                  // lane's float offset in chunk

    float r[64];
#pragma unroll
    for (int v = 0; v < 64; ++v) r[v] = 0.0f;

    // x row pointers for this wave's 4 tokens (per-lane, as in R8 — proven)
    const float* xr0 = x + (size_t)(block_base + w * 4 + 0) * DIM + lane4;
    const float* xr1 = xr0 + DIM;
    const float* xr2 = xr1 + DIM;
    const float* xr3 = xr2 + DIM;

    // ---- prologue: x chunk 0 into regs (nontemporal: no L2 pollution) ----
    fvec4 xv0 = __builtin_nontemporal_load((const fvec4*)xr0);
    fvec4 xv1 = __builtin_nontemporal_load((const fvec4*)xr1);
    fvec4 xv2 = __builtin_nontemporal_load((const fvec4*)xr2);
    fvec4 xv3 = __builtin_nontemporal_load((const fvec4*)xr3);

#pragma unroll
    for (int c = 0; c < NCHUNK; ++c) {
        fvec4 xn0, xn1, xn2, xn3;
        if (c + 1 < NCHUNK) {
            const int off = (c + 1) * CHUNK;
            xn0 = __builtin_nontemporal_load((const fvec4*)(xr0 + off));
            xn1 = __builtin_nontemporal_load((const fvec4*)(xr1 + off));
            xn2 = __builtin_nontemporal_load((const fvec4*)(xr2 + off));
            xn3 = __builtin_nontemporal_load((const fvec4*)(xr3 + off));
        }

        // ---- compute chunk c: 16 experts x 4 tokens (order == R8) ----
        // W[e*DIM + c*CHUNK + lane4]: uniform base W (SGPR pair) + constant
        // + lane4 voffset => saddr-form L2-hit loads, no per-lane pointers.
#pragma unroll
        for (int eb = 0; eb < NEXP; eb += 2) {
            fvec4 wa = *(const fvec4*)&W[(eb + 0) * DIM + c * CHUNK + lane4];
            fvec4 wc = *(const fvec4*)&W[(eb + 1) * DIM + c * CHUNK + lane4];
#define FMA4(acc, xv, wv) acc = fmaf((xv).x,(wv).x, fmaf((xv).y,(wv).y, \
                                fmaf((xv).z,(wv).z, fmaf((xv).w,(wv).w,(acc)))))
            FMA4(r[0 * 16 + eb],     xv0, wa);
            FMA4(r[1 * 16 + eb],     xv1, wa);
            FMA4(r[2 * 16 + eb],     xv2, wa);
            FMA4(r[3 * 16 + eb],     xv3, wa);
            FMA4(r[0 * 16 + eb + 1], xv0, wc);
            FMA4(r[1 * 16 + eb + 1], xv1, wc);
            FMA4(r[2 * 16 + eb + 1], xv2, wc);
            FMA4(r[3 * 16 + eb + 1], xv3, wc);
#undef FMA4
        }
        if (c + 1 < NCHUNK) { xv0 = xn0; xv1 = xn1; xv2 = xn2; xv3 = xn3; }
    }

    // ---- butterfly reduce-scatter over 64 lanes: after stage s, r[i]
    // holds the partial for value v = (i << (s+1)) + (lane & ((2<<s)-1)).
    // Final: lane L holds the full sum for v = L = t*16 + e. ----
#pragma unroll
    for (int s = 0; s < 6; ++s) {
        const int dist = 1 << s;
        const bool bsel = (lane >> s) & 1;
        const int n = 64 >> (s + 1);
#pragma unroll
        for (int i = 0; i < n; ++i) {
            float keep = bsel ? r[2 * i + 1] : r[2 * i];
            float send = bsel ? r[2 * i]     : r[2 * i + 1];
            r[i] = keep + __shfl_xor(send, dist);
        }
    }

    // ---- epilogue: lane L -> (t = L>>4, e = L&15) of this wave ----
    const int e = lane & 15;
    const size_t obase = (size_t)block_base * NEXP + (size_t)w * 64;
    float nz    = noise[obase + lane];          // noise[t][e], coalesced
    float noisy = r[0] + b[e] + 0.1f * nz;

    // Top-2 across the 16 lanes of the token group (xor 1,2,4,8 stays inside).
    float v1 = noisy; int i1 = e;
    float v2 = -INFINITY; int i2 = 999;
#pragma unroll
    for (int s = 0; s < 4; ++s) {
        const int d = 1 << s;
        float ov1 = __shfl_xor(v1, d); int oi1 = __shfl_xor(i1, d);
        float ov2 = __shfl_xor(v2, d); int oi2 = __shfl_xor(i2, d);
        bool awin = (v1 > ov1) || (v1 == ov1 && i1 < oi1);
        float t1v = awin ? v1  : ov1;  int t1i = awin ? i1  : oi1;
        float lv  = awin ? ov1 : v1;   int li  = awin ? oi1 : i1;
        float cv  = awin ? v2  : ov2;  int ci  = awin ? i2  : oi2;
        bool bwin = (cv > lv) || (cv == lv && ci < li);
        v1 = t1v; i1 = t1i;
        v2 = bwin ? cv : lv; i2 = bwin ? ci : li;
    }

    float dd = __expf(v2 - v1);
    float w1 = 1.0f / (1.0f + dd);
    float w2 = dd * w1;

    float o = (e == i1) ? w1 : ((e == i2) ? w2 : 0.0f);
    out[obase + lane] = o;   // out[t*16 + e], 256B contiguous per wave
}

extern "C" void kernel_launch(void* const* d_in, const int* in_sizes, int n_in,
                              void* d_out, int out_size, void* d_ws, size_t ws_size,
                              hipStream_t stream) {
    const float* x     = (const float*)d_in[0];
    const float* noise = (const float*)d_in[1];
    const float* W     = (const float*)d_in[2];
    const float* b     = (const float*)d_in[3];
    float* out = (float*)d_out;

    dim3 grid(TOKENS / TPB);   // 1024 blocks, 3 resident/CU
    dim3 block(NWAVE * 64);    // 256 threads
    gating_moe_kernel<<<grid, block, 0, stream>>>(x, noise, W, b, out);
}

// Round 6
// 188.257 us; speedup vs baseline: 1.1551x; 1.1551x over previous
//
#include <hip/hip_runtime.h>
#include <hip/hip_bf16.h>
#include <math.h>

#define TOKENS 16384
#define DIM    2048
#define NEXP   16
#define CHUNK  256                 // K-floats per chunk (1 KB per row)
#define NCHUNK (DIM / CHUNK)       // 8
#define TPB    16                  // tokens per block
#define NWAVE  4                   // waves per block (256 thr)

typedef float fvec4 __attribute__((ext_vector_type(4)));
typedef float f32_as1 __attribute__((address_space(1)));
typedef float f32_as3 __attribute__((address_space(3)));

// Async DMA: 64 lanes x 16 B -> 1 KB LDS row (wave-uniform base + lane*16).
__device__ __forceinline__ void async_row(const float* gp, float* lp) {
    __builtin_amdgcn_global_load_lds((const f32_as1*)(const void*)gp,
                                     (f32_as3*)(uintptr_t)lp, 16, 0, 0);
}

// R14 = exact revert to R8, the proven-best kernel (188.4/190.0 us headline).
// Session ledger for why each "improvement" regressed:
//   R9  whole-W-in-LDS (128KB, 1 blk/CU): no placement slack, 195us.
//   R10 triple-buf + vmcnt(36): FIFO miscount (4 x-loads/thread not 16)
//       => barrier never waited => race/container loss.
//   R11/R13 global-W, no LDS: e*DIM offsets (8..120KB) exceed the 13-bit
//       global_load imm => ~15 materialized address regs => r[64] spills
//       (VGPR=84, scratch WRITE 8.4MB), 79us kernel, 217us headline.
//   R12 counted vmcnt(4) + sched_barrier(0) pins: defeats compiler
//       scheduling (m141 signature), ~45us kernel, 200us headline.
// Structure: x (HBM, no reuse) -> VGPR nontemporal loads, 1-chunk prefetch;
// W (L2-resident) -> 2x16KB LDS double-buffer via global_load_lds; the
// per-chunk __syncthreads waits on the cheap L2 staging, and x_{c+1} is
// issued ~2048 wall-cycles before the drain so most latency is covered.
// Wave = 64-lane k-split x 4 tokens; acc r[64]=(t,e); 4 blocks/CU.
// Epilogue: 6-stage butterfly reduce-scatter + 16-lane top-2 + softmax.
__global__ __launch_bounds__(256, 4) void gating_moe_kernel(
    const float* __restrict__ x,
    const float* __restrict__ noise,
    const float* __restrict__ W,
    const float* __restrict__ b,
    float* __restrict__ out)
{
    __shared__ __align__(16) fvec4 wbuf[2][NEXP][CHUNK / 4];  // 2 x 16 KB

    const int tid  = threadIdx.x;
    const int lane = tid & 63;
    const int w    = tid >> 6;                   // wave 0..3
    const int block_base = blockIdx.x * TPB;
    const int lane4 = lane * 4;                  // lane's float offset in chunk

    float r[64];
#pragma unroll
    for (int v = 0; v < 64; ++v) r[v] = 0.0f;

    // x row pointers for this wave's 4 tokens
    const float* xr0 = x + (size_t)(block_base + w * 4 + 0) * DIM + lane4;
    const float* xr1 = xr0 + DIM;
    const float* xr2 = xr1 + DIM;
    const float* xr3 = xr2 + DIM;

    // ---- prologue: stage W chunk 0; load x chunk 0 into regs ----
#pragma unroll
    for (int q = 0; q < 4; ++q) {
        const int e = w * 4 + q;
        async_row(W + (size_t)e * DIM + lane4, (float*)&wbuf[0][e][0]);
    }
    fvec4 xv0 = __builtin_nontemporal_load((const fvec4*)xr0);
    fvec4 xv1 = __builtin_nontemporal_load((const fvec4*)xr1);
    fvec4 xv2 = __builtin_nontemporal_load((const fvec4*)xr2);
    fvec4 xv3 = __builtin_nontemporal_load((const fvec4*)xr3);
    __syncthreads();

#pragma unroll
    for (int c = 0; c < NCHUNK; ++c) {
        const int cur = c & 1, nxt = cur ^ 1;
        fvec4 xn0, xn1, xn2, xn3;
        if (c + 1 < NCHUNK) {
            // stage W chunk c+1 (L2 hit) + prefetch x chunk c+1 to regs
#pragma unroll
            for (int q = 0; q < 4; ++q) {
                const int e = w * 4 + q;
                async_row(W + (size_t)e * DIM + (c + 1) * CHUNK + lane4,
                          (float*)&wbuf[nxt][e][0]);
            }
            const int off = (c + 1) * CHUNK;
            xn0 = __builtin_nontemporal_load((const fvec4*)(xr0 + off));
            xn1 = __builtin_nontemporal_load((const fvec4*)(xr1 + off));
            xn2 = __builtin_nontemporal_load((const fvec4*)(xr2 + off));
            xn3 = __builtin_nontemporal_load((const fvec4*)(xr3 + off));
        }

        // ---- compute chunk c: 16 experts x 4 tokens ----
#pragma unroll
        for (int eb = 0; eb < NEXP; eb += 2) {
            fvec4 wa = wbuf[cur][eb + 0][lane];
            fvec4 wc = wbuf[cur][eb + 1][lane];
#define FMA4(acc, xv, wv) acc = fmaf((xv).x,(wv).x, fmaf((xv).y,(wv).y, \
                                fmaf((xv).z,(wv).z, fmaf((xv).w,(wv).w,(acc)))))
            FMA4(r[0  * 16 + eb],     xv0, wa);
            FMA4(r[1  * 16 + eb],     xv1, wa);
            FMA4(r[2  * 16 + eb],     xv2, wa);
            FMA4(r[3  * 16 + eb],     xv3, wa);
            FMA4(r[0  * 16 + eb + 1], xv0, wc);
            FMA4(r[1  * 16 + eb + 1], xv1, wc);
            FMA4(r[2  * 16 + eb + 1], xv2, wc);
            FMA4(r[3  * 16 + eb + 1], xv3, wc);
#undef FMA4
        }
        __syncthreads();   // waits W staging of c+1 (L2-cheap); guards buffers
        if (c + 1 < NCHUNK) { xv0 = xn0; xv1 = xn1; xv2 = xn2; xv3 = xn3; }
    }

    // ---- butterfly reduce-scatter over 64 lanes: after stage s, r[i]
    // holds the partial for value v = (i << (s+1)) + (lane & ((2<<s)-1)).
    // Final: lane L holds the full sum for v = L = t*16 + e. ----
#pragma unroll
    for (int s = 0; s < 6; ++s) {
        const int dist = 1 << s;
        const bool bsel = (lane >> s) & 1;
        const int n = 64 >> (s + 1);
#pragma unroll
        for (int i = 0; i < n; ++i) {
            float keep = bsel ? r[2 * i + 1] : r[2 * i];
            float send = bsel ? r[2 * i]     : r[2 * i + 1];
            r[i] = keep + __shfl_xor(send, dist);
        }
    }

    // ---- epilogue: lane L -> (t = L>>4, e = L&15) of this wave ----
    const int e = lane & 15;
    const size_t obase = (size_t)block_base * NEXP + (size_t)w * 64;
    float nz    = noise[obase + lane];          // noise[t][e], coalesced
    float noisy = r[0] + b[e] + 0.1f * nz;

    // Top-2 across the 16 lanes of the token group (xor 1,2,4,8 stays inside).
    float v1 = noisy; int i1 = e;
    float v2 = -INFINITY; int i2 = 999;
#pragma unroll
    for (int s = 0; s < 4; ++s) {
        const int d = 1 << s;
        float ov1 = __shfl_xor(v1, d); int oi1 = __shfl_xor(i1, d);
        float ov2 = __shfl_xor(v2, d); int oi2 = __shfl_xor(i2, d);
        bool awin = (v1 > ov1) || (v1 == ov1 && i1 < oi1);
        float t1v = awin ? v1  : ov1;  int t1i = awin ? i1  : oi1;
        float lv  = awin ? ov1 : v1;   int li  = awin ? oi1 : i1;
        float cv  = awin ? v2  : ov2;  int ci  = awin ? i2  : oi2;
        bool bwin = (cv > lv) || (cv == lv && ci < li);
        v1 = t1v; i1 = t1i;
        v2 = bwin ? cv : lv; i2 = bwin ? ci : li;
    }

    float dd = __expf(v2 - v1);
    float w1 = 1.0f / (1.0f + dd);
    float w2 = dd * w1;

    float o = (e == i1) ? w1 : ((e == i2) ? w2 : 0.0f);
    out[obase + lane] = o;   // out[t*16 + e], 256B contiguous per wave
}

extern "C" void kernel_launch(void* const* d_in, const int* in_sizes, int n_in,
                              void* d_out, int out_size, void* d_ws, size_t ws_size,
                              hipStream_t stream) {
    const float* x     = (const float*)d_in[0];
    const float* noise = (const float*)d_in[1];
    const float* W     = (const float*)d_in[2];
    const float* b     = (const float*)d_in[3];
    float* out = (float*)d_out;

    dim3 grid(TOKENS / TPB);   // 1024 blocks
    dim3 block(NWAVE * 64);    // 256 threads
    gating_moe_kernel<<<grid, block, 0, stream>>>(x, noise, W, b, out);
}